// Round 17
// baseline (117.389 us; speedup 1.0000x reference)
//
#include <hip/hip_runtime.h>
#include <math.h>

#define Hh 512
#define Ww 512
#define Bb 8
#define CI 32
#define CO 32
#define HM 16   // kx modes kept
#define KYp 32  // packed ky modes (0..15 and 496..511)

static constexpr float TWO_PI = 6.28318530717958647692f;

// workspace layout (float offsets)
#define F_OFF  4194304u   // [B*CI][32][16][2] = 262,144 floats
#define G_OFF  4456448u   // [B*CO][32][16][2] = 262,144 floats (1 MB)
#define g_OFF  4718592u   // E tables live here
// E   (bf16 phase-1 DFT frags, 32 KB)  at g_OFF
// E2c (bf16 phase-2 DFT frags, 64 KB)  at g_OFF + 8192
// T2f (bf16 t2 B-frags,        32 KB)  at g_OFF + 24576

using short8 = __attribute__((ext_vector_type(8))) short;
using f32x16 = __attribute__((ext_vector_type(16))) float;
using f32x4  = __attribute__((ext_vector_type(4))) float;

__device__ inline unsigned short bf16_rn(float f) {
  unsigned u = __float_as_uint(f);
  u += 0x7FFFu + ((u >> 16) & 1u);
  return (unsigned short)(u >> 16);
}

// exact split of 4 floats into hi(bf16-trunc) + lo(residual as bf16)
__device__ inline void split4(float4 v, uint2& h2, uint2& l2) {
  unsigned u0 = __float_as_uint(v.x), u1 = __float_as_uint(v.y);
  unsigned u2 = __float_as_uint(v.z), u3 = __float_as_uint(v.w);
  float f0 = v.x - __uint_as_float(u0 & 0xFFFF0000u);
  float f1 = v.y - __uint_as_float(u1 & 0xFFFF0000u);
  float f2 = v.z - __uint_as_float(u2 & 0xFFFF0000u);
  float f3 = v.w - __uint_as_float(u3 & 0xFFFF0000u);
  h2.x = (u1 & 0xFFFF0000u) | (u0 >> 16);
  h2.y = (u3 & 0xFFFF0000u) | (u2 >> 16);
  l2.x = (__float_as_uint(f1) & 0xFFFF0000u) | (__float_as_uint(f0) >> 16);
  l2.y = (__float_as_uint(f3) & 0xFFFF0000u) | (__float_as_uint(f2) >> 16);
}

// --------- E init: all DFT-matrix fragment tables ------------------------
__global__ __launch_bounds__(256) void e_init_kernel(float* __restrict__ Ef) {
  unsigned short* E = (unsigned short*)Ef;
  int idx = blockIdx.x * 256 + threadIdx.x;   // 0..65535
  if (idx < 16384) {
    int kk = idx >> 9;
    int l = (idx >> 3) & 63;
    int j = idx & 7;
    int k = kk * 16 + 8 * (l >> 5) + j;
    int col = l & 31;
    int kx = col >> 1;
    int t = (kx * k) & 511;
    float sv, cv;
    sincosf(TWO_PI * (float)t / 512.0f, &sv, &cv);
    E[idx] = bf16_rn((col & 1) ? -sv : cv);
  } else if (idx < 49152) {
    int idx2 = idx - 16384;
    int mt = idx2 >> 14;
    int rem = idx2 & 16383;
    int kk = rem >> 9;
    int l = (rem >> 3) & 63;
    int j = rem & 7;
    int h = kk * 16 + 8 * (l >> 5) + j;
    int kyc = l & 31;
    int kyp = mt * 16 + (kyc >> 1);
    int ky = (kyp < 16) ? kyp : (kyp + 480);
    int t = (ky * h) & 511;
    float sv, cv;
    sincosf(TWO_PI * (float)t / 512.0f, &sv, &cv);
    E[idx] = bf16_rn((kyc & 1) ? -sv : cv);
  } else {
    int rem = idx - 49152;                 // 0..16383
    int ntile = rem >> 10;
    int s = (rem >> 9) & 1;
    int l = (rem >> 3) & 63;
    int j = rem & 7;
    int K = s * 16 + 8 * (l >> 5) + j;
    int k = K >> 1, c = K & 1;
    int w = ntile * 32 + (l & 31);
    int t = (k * w) & 511;
    float sv, cv;
    sincosf(TWO_PI * (float)t / 512.0f, &sv, &cv);
    float wk = (k == 0) ? 1.0f : 2.0f;
    float inv = 1.0f / 262144.0f;
    E[idx] = bf16_rn(inv * wk * (c ? -sv : cv));
  }
}

// ---------------- fwd: x image -> F (unchanged from round 5) -------------
__global__ __launch_bounds__(512) void fwd_kernel(const float* __restrict__ x,
                                                  const float* __restrict__ Ef,
                                                  const float* __restrict__ E2f,
                                                  float* __restrict__ F) {
  __shared__ char lds[135168];
  short* E2l = (short*)lds;                 // [mt 2][kk 32][64][8]  64 KB
  short* Xh  = (short*)(lds + 65536);       // [kc 32][64][8]        32 KB
  short* Xl  = (short*)(lds + 98304);       //                       32 KB
  float* red = (float*)(lds + 65536);       // alias Xh
  short* Ah  = (short*)(lds + 131072);      // [kc2 2][64][8]         2 KB
  short* Al  = (short*)(lds + 133120);      //                        2 KB
  float* Pbuf = (float*)(lds + 65536);      // final reduce (alias)

  const int tid = threadIdx.x;
  const int l = tid & 63;
  const int wid = tid >> 6;
  const int bi = blockIdx.x;
  const float* xb = x + (size_t)bi * (Hh * Ww);

  {
    const float4* Eg = (const float4*)E2f;
    float4* El4 = (float4*)E2l;
    #pragma unroll
    for (int j = 0; j < 8; ++j) El4[tid + j * 512] = Eg[tid + j * 512];
  }
  short8 e1[4];
  {
    const short* Eg = (const short*)Ef;
    #pragma unroll
    for (int c = 0; c < 4; ++c)
      e1[c] = *(const short8*)(Eg + ((size_t)(4 * wid + c) * 64 + l) * 8);
  }

  const int hb = (l >> 1) & 1;
  const int jfr = 4 * (l & 1);
  const int kc0 = l >> 2;

  float4 rv[8];
  #pragma unroll
  for (int j = 0; j < 4; ++j) {
    const float* rowp = xb + (size_t)(wid * 4 + j) * 512;
    rv[2 * j]     = *(const float4*)(rowp + 4 * l);
    rv[2 * j + 1] = *(const float4*)(rowp + 256 + 4 * l);
  }

  f32x16 acc1 = {0.f,0.f,0.f,0.f,0.f,0.f,0.f,0.f,0.f,0.f,0.f,0.f,0.f,0.f,0.f,0.f};
  f32x16 acc2 = {0.f,0.f,0.f,0.f,0.f,0.f,0.f,0.f,0.f,0.f,0.f,0.f,0.f,0.f,0.f,0.f};

  const int mt2 = wid & 1, kc2w = (wid >> 1) & 1, part2 = wid >> 2;

  for (int s = 0; s < 16; ++s) {
    if (s > 0) {
      short8 a2 = *(const short8*)&E2l[((mt2 * 32 + ((s - 1) * 2 + kc2w)) * 64 + l) * 8];
      short8 b2 = part2 ? *(const short8*)&Al[(kc2w * 64 + l) * 8]
                        : *(const short8*)&Ah[(kc2w * 64 + l) * 8];
      acc2 = __builtin_amdgcn_mfma_f32_32x32x16_bf16(a2, b2, acc2, 0, 0, 0);
    }
    #pragma unroll
    for (int j = 0; j < 4; ++j) {
      #pragma unroll
      for (int hf = 0; hf < 2; ++hf) {
        int kc = hf * 16 + kc0;
        int lanep = (wid * 4 + j) + 32 * hb;
        int off = ((kc * 64) + (lanep ^ (kc & 7))) * 8 + jfr;
        uint2 h2, l2;
        split4(rv[2 * j + hf], h2, l2);
        *(uint2*)&Xh[off] = h2;
        *(uint2*)&Xl[off] = l2;
      }
    }
    if (s < 15) {
      #pragma unroll
      for (int j = 0; j < 4; ++j) {
        const float* rowp = xb + (size_t)((s + 1) * 32 + wid * 4 + j) * 512;
        rv[2 * j]     = *(const float4*)(rowp + 4 * l);
        rv[2 * j + 1] = *(const float4*)(rowp + 256 + 4 * l);
      }
    }
    __syncthreads();
    #pragma unroll
    for (int c = 0; c < 4; ++c) {
      int kc = 4 * wid + c;
      int slot = ((kc * 64) + (l ^ (kc & 7))) * 8;
      short8 hi = *(const short8*)&Xh[slot];
      short8 lo = *(const short8*)&Xl[slot];
      acc1 = __builtin_amdgcn_mfma_f32_32x32x16_bf16(hi, e1[c], acc1, 0, 0, 0);
      acc1 = __builtin_amdgcn_mfma_f32_32x32x16_bf16(lo, e1[c], acc1, 0, 0, 0);
    }
    __syncthreads();
    #pragma unroll
    for (int q = 0; q < 4; ++q)
      *(float4*)&red[((wid * 4 + q) * 64 + l) * 4] =
          make_float4(acc1[4*q], acc1[4*q+1], acc1[4*q+2], acc1[4*q+3]);
    #pragma unroll
    for (int r = 0; r < 16; ++r) acc1[r] = 0.f;
    __syncthreads();
    if (wid < 4) {
      const int q = wid;
      float4 sum = make_float4(0.f, 0.f, 0.f, 0.f);
      #pragma unroll
      for (int w = 0; w < 8; ++w) {
        float4 v = *(const float4*)&red[((w * 4 + q) * 64 + l) * 4];
        sum.x += v.x; sum.y += v.y; sum.z += v.z; sum.w += v.w;
      }
      uint2 h2, l2;
      split4(sum, h2, l2);
      int off = ((q >> 1) * 64 + ((l & 31) + 32 * (q & 1))) * 8 + 4 * (l >> 5);
      *(uint2*)&Ah[off] = h2;
      *(uint2*)&Al[off] = l2;
    }
    __syncthreads();
  }
  {
    short8 a2 = *(const short8*)&E2l[((mt2 * 32 + (15 * 2 + kc2w)) * 64 + l) * 8];
    short8 b2 = part2 ? *(const short8*)&Al[(kc2w * 64 + l) * 8]
                      : *(const short8*)&Ah[(kc2w * 64 + l) * 8];
    acc2 = __builtin_amdgcn_mfma_f32_32x32x16_bf16(a2, b2, acc2, 0, 0, 0);
  }
  #pragma unroll
  for (int r4 = 0; r4 < 4; ++r4)
    *(float4*)&Pbuf[((wid * 4 + r4) * 64 + l) * 4] =
        make_float4(acc2[4*r4], acc2[4*r4+1], acc2[4*r4+2], acc2[4*r4+3]);
  __syncthreads();

  if (wid < 2) {
    const int mt = wid;
    float S[16];
    #pragma unroll
    for (int r = 0; r < 16; ++r) S[r] = 0.f;
    #pragma unroll
    for (int p = 0; p < 4; ++p) {
      #pragma unroll
      for (int r4 = 0; r4 < 4; ++r4) {
        float4 v = *(const float4*)&Pbuf[(((mt + 2 * p) * 4 + r4) * 64 + l) * 4];
        S[4*r4]   += v.x; S[4*r4+1] += v.y; S[4*r4+2] += v.z; S[4*r4+3] += v.w;
      }
    }
    const int c = l & 1;
    #pragma unroll
    for (int q = 0; q < 8; ++q) {
      int r0 = 2 * q;
      float T = __shfl_xor(S[r0 + 1], 1, 64);
      float val = c ? (S[r0] + T) : (S[r0] - T);
      int kyp_loc = ((r0 & 3) >> 1) + 4 * (r0 >> 2) + 2 * (l >> 5);
      F[((size_t)bi * 32 + mt * 16 + kyp_loc) * 32 + (l & 31)] = val;
    }
  }
}

// ---------------- mix: F -> G (hoisted; identical fmaf chain) ------------
__global__ __launch_bounds__(512) void mix_kernel(const float* __restrict__ F,
    const float* __restrict__ w1r, const float* __restrict__ w1i,
    const float* __restrict__ w2r, const float* __restrict__ w2i,
    float* __restrict__ G) {
  const int tid = threadIdx.x;
  const int b = blockIdx.x >> 5;
  const int o = blockIdx.x & 31;
  const int kyp = tid >> 4;
  const int kx = tid & 15;
  const bool top = kyp < 16;
  const int m = top ? kyp : (kyp - 16);
  const float* wr = top ? w1r : w2r;
  const float* wi = top ? w1i : w2i;
  float gr = 0.f, gi = 0.f;
  for (int i = 0; i < CI; ++i) {
    float2 f = *(const float2*)&F[(((size_t)b * CI + i) * KYp + kyp) * (HM * 2) + kx * 2];
    size_t wo = (((size_t)i * CO + o) * HM + m) * HM + kx;
    float wrv = wr[wo], wiv = wi[wo];
    gr = fmaf(f.x, wrv, gr); gr = fmaf(-f.y, wiv, gr);
    gi = fmaf(f.x, wiv, gi); gi = fmaf(f.y, wrv, gi);
  }
  size_t go = ((size_t)blockIdx.x * KYp + kyp) * (HM * 2) + kx * 2;
  *(float2*)(G + go) = make_float2(gr, gi);
}

// ---------------- bwd: G -> y. 512 blocks of 256 rows (b,o,half) —
//  SINGLE scheduling round (2 blocks/CU x 256 CU = 512): no round
//  boundaries, so the one t1 compute phase happens during ramp and the
//  NT store stream runs uninterrupted. t1 = R11's 8-kx structure
//  (bit-identical fmaf chain); t2 = direct NT stores (R16).
__global__ __launch_bounds__(512, 4) void bwd_kernel(const float* __restrict__ G,
    const float* __restrict__ bias, const float* __restrict__ T2f,
    float* __restrict__ y) {
  __shared__ char lds[40960];
  short* Ah   = (short*)lds;                // [mt 8][s 2][64][8]    16 KB
  short* Al   = (short*)(lds + 16384);      //                       16 KB
  float* Gs   = (float*)(lds + 32768);      // [kyp 32][kx 16][2]     4 KB
  float* ct   = (float*)(lds + 36864);      // 2 KB
  float* st   = (float*)(lds + 38912);      // 2 KB

  const int tid = threadIdx.x;
  const int l = tid & 63;
  const int wid = tid >> 6;
  const int bo = blockIdx.x >> 1;      // b*CO + o
  const int half = blockIdx.x & 1;     // row half (h in [half*256, +256))
  const int o = bo & 31;
  const float bv = bias[o];

  // B-fragments for this wave's 2 ntiles -> 16 VGPRs
  short8 bfr[4];
  {
    const short* Tg = (const short*)T2f;
    #pragma unroll
    for (int q = 0; q < 4; ++q) {
      int nt = wid * 2 + (q >> 1);
      int s = q & 1;
      bfr[q] = *(const short8*)(Tg + ((size_t)(nt * 2 + s) * 64 + l) * 8);
    }
  }
  // twiddle table + G stage (4 KB)
  {
    float sv, cv;
    sincosf(TWO_PI * (float)tid / 512.0f, &sv, &cv);
    ct[tid] = cv;
    st[tid] = sv;
    if (tid < 256)
      ((float4*)Gs)[tid] = ((const float4*)(G + (size_t)bo * (KYp * HM * 2)))[tid];
  }
  __syncthreads();

  // ---- t1: thread = (row r in half, kx-half); 8 kx each (bit-identical
  //      fmaf chain per element, as R10/R11) ----
  {
    const int r = tid & 255;           // row within half
    const int h = half * 256 + r;
    const int kxh = tid >> 8;          // kx 8*kxh .. 8*kxh+7
    float gr[8], gi[8];
    #pragma unroll
    for (int k = 0; k < 8; ++k) { gr[k] = 0.f; gi[k] = 0.f; }
    #pragma unroll 4
    for (int kyp = 0; kyp < 32; ++kyp) {
      const int ky = (kyp < 16) ? kyp : (kyp + 480);
      const int t = (ky * h) & 511;
      const float cc = ct[t], ss = st[t];
      float4 row[4];
      #pragma unroll
      for (int j = 0; j < 4; ++j) row[j] = *(const float4*)&Gs[kyp * 32 + kxh * 16 + j * 4];
      #pragma unroll
      for (int k = 0; k < 8; ++k) {
        float Gr = ((const float*)row)[2 * k];
        float Gi = ((const float*)row)[2 * k + 1];
        gr[k] = fmaf(Gr, cc, gr[k]); gr[k] = fmaf(-Gi, ss, gr[k]);
        gi[k] = fmaf(Gr, ss, gi[k]); gi[k] = fmaf(Gi, cc, gi[k]);
      }
    }
    // frag write: s = kxh; K = s*16 + 8*hf2 + j
    const int mt_loc = r >> 5;
    const int rr = r & 31;
    const int s = kxh;
    #pragma unroll
    for (int hf2 = 0; hf2 < 2; ++hf2) {
      int k0 = hf2 * 4;   // local kx
      float4 va = make_float4(gr[k0], gi[k0], gr[k0 + 1], gi[k0 + 1]);
      float4 vb = make_float4(gr[k0 + 2], gi[k0 + 2], gr[k0 + 3], gi[k0 + 3]);
      uint2 ha, la, hb, lb;
      split4(va, ha, la);
      split4(vb, hb, lb);
      int off = ((mt_loc * 2 + s) * 64 + rr + 32 * hf2) * 8;
      *(uint4*)&Ah[off] = make_uint4(ha.x, ha.y, hb.x, hb.y);
      *(uint4*)&Al[off] = make_uint4(la.x, la.y, lb.x, lb.y);
    }
  }
  __syncthreads();

  // ---- t2: per mtile: 2 MFMA accs -> direct NT stores (no staging) ----
  {
    float* yb = y + (size_t)bo * (Hh * Ww) + (size_t)half * 256 * Ww;
    const int colA = (wid * 2) * 32 + (l & 31);
    const int colB = (wid * 2 + 1) * 32 + (l & 31);
    const int rq = 4 * (l >> 5);
    for (int mt = 0; mt < 8; ++mt) {
      short8 a_h0 = *(const short8*)&Ah[((mt * 2 + 0) * 64 + l) * 8];
      short8 a_l0 = *(const short8*)&Al[((mt * 2 + 0) * 64 + l) * 8];
      short8 a_h1 = *(const short8*)&Ah[((mt * 2 + 1) * 64 + l) * 8];
      short8 a_l1 = *(const short8*)&Al[((mt * 2 + 1) * 64 + l) * 8];
      f32x16 accA, accB;
      #pragma unroll
      for (int r = 0; r < 16; ++r) { accA[r] = bv; accB[r] = bv; }
      accA = __builtin_amdgcn_mfma_f32_32x32x16_bf16(a_h0, bfr[0], accA, 0, 0, 0);
      accA = __builtin_amdgcn_mfma_f32_32x32x16_bf16(a_l0, bfr[0], accA, 0, 0, 0);
      accA = __builtin_amdgcn_mfma_f32_32x32x16_bf16(a_h1, bfr[1], accA, 0, 0, 0);
      accA = __builtin_amdgcn_mfma_f32_32x32x16_bf16(a_l1, bfr[1], accA, 0, 0, 0);
      accB = __builtin_amdgcn_mfma_f32_32x32x16_bf16(a_h0, bfr[2], accB, 0, 0, 0);
      accB = __builtin_amdgcn_mfma_f32_32x32x16_bf16(a_l0, bfr[2], accB, 0, 0, 0);
      accB = __builtin_amdgcn_mfma_f32_32x32x16_bf16(a_h1, bfr[3], accB, 0, 0, 0);
      accB = __builtin_amdgcn_mfma_f32_32x32x16_bf16(a_l1, bfr[3], accB, 0, 0, 0);
      #pragma unroll
      for (int r = 0; r < 16; ++r) {
        int row = mt * 32 + (r & 3) + 8 * (r >> 2) + rq;
        __builtin_nontemporal_store(accA[r], &yb[(size_t)row * Ww + colA]);
        __builtin_nontemporal_store(accB[r], &yb[(size_t)row * Ww + colB]);
      }
    }
  }
}

extern "C" void kernel_launch(void* const* d_in, const int* in_sizes, int n_in,
                              void* d_out, int out_size, void* d_ws, size_t ws_size,
                              hipStream_t stream) {
  const float* x    = (const float*)d_in[0];
  const float* w1r  = (const float*)d_in[1];
  const float* w1i  = (const float*)d_in[2];
  const float* w2r  = (const float*)d_in[3];
  const float* w2i  = (const float*)d_in[4];
  const float* bias = (const float*)d_in[5];
  float* y  = (float*)d_out;
  float* ws = (float*)d_ws;
  float* F   = ws + F_OFF;
  float* G   = ws + G_OFF;
  float* E   = ws + g_OFF;           // 32 KB
  float* E2c = ws + g_OFF + 8192;    // 64 KB
  float* T2f = ws + g_OFF + 24576;   // 32 KB

  hipLaunchKernelGGL(e_init_kernel, dim3(256), dim3(256), 0, stream, E);
  hipLaunchKernelGGL(fwd_kernel, dim3(Bb * CI), dim3(512), 0, stream, x, E, E2c, F);
  hipLaunchKernelGGL(mix_kernel, dim3(Bb * CO), dim3(512), 0, stream, F,
                     w1r, w1i, w2r, w2i, G);
  hipLaunchKernelGGL(bwd_kernel, dim3(Bb * CO * 2), dim3(512), 0, stream, G,
                     bias, T2f, y);
}

// Round 18
// 109.743 us; speedup vs baseline: 1.0697x; 1.0697x over previous
//
#include <hip/hip_runtime.h>
#include <math.h>

#define Hh 512
#define Ww 512
#define Bb 8
#define CI 32
#define CO 32
#define HM 16   // kx modes kept
#define KYp 32  // packed ky modes (0..15 and 496..511)

static constexpr float TWO_PI = 6.28318530717958647692f;

// workspace layout (float offsets)
#define F_OFF  4194304u   // [B*CI][32][16][2] = 262,144 floats
#define G_OFF  4456448u   // [B*CO][32][16][2] = 262,144 floats (1 MB)
#define g_OFF  4718592u   // E tables live here
// E   (bf16 phase-1 DFT frags, 32 KB)  at g_OFF
// E2c (bf16 phase-2 DFT frags, 64 KB)  at g_OFF + 8192
// T2f (bf16 t2 B-frags,        32 KB)  at g_OFF + 24576

using short8 = __attribute__((ext_vector_type(8))) short;
using f32x16 = __attribute__((ext_vector_type(16))) float;
using f32x4  = __attribute__((ext_vector_type(4))) float;

__device__ inline unsigned short bf16_rn(float f) {
  unsigned u = __float_as_uint(f);
  u += 0x7FFFu + ((u >> 16) & 1u);
  return (unsigned short)(u >> 16);
}

// exact split of 4 floats into hi(bf16-trunc) + lo(residual as bf16)
__device__ inline void split4(float4 v, uint2& h2, uint2& l2) {
  unsigned u0 = __float_as_uint(v.x), u1 = __float_as_uint(v.y);
  unsigned u2 = __float_as_uint(v.z), u3 = __float_as_uint(v.w);
  float f0 = v.x - __uint_as_float(u0 & 0xFFFF0000u);
  float f1 = v.y - __uint_as_float(u1 & 0xFFFF0000u);
  float f2 = v.z - __uint_as_float(u2 & 0xFFFF0000u);
  float f3 = v.w - __uint_as_float(u3 & 0xFFFF0000u);
  h2.x = (u1 & 0xFFFF0000u) | (u0 >> 16);
  h2.y = (u3 & 0xFFFF0000u) | (u2 >> 16);
  l2.x = (__float_as_uint(f1) & 0xFFFF0000u) | (__float_as_uint(f0) >> 16);
  l2.y = (__float_as_uint(f3) & 0xFFFF0000u) | (__float_as_uint(f2) >> 16);
}

// --------- E init: all DFT-matrix fragment tables ------------------------
__global__ __launch_bounds__(256) void e_init_kernel(float* __restrict__ Ef) {
  unsigned short* E = (unsigned short*)Ef;
  int idx = blockIdx.x * 256 + threadIdx.x;   // 0..65535
  if (idx < 16384) {
    int kk = idx >> 9;
    int l = (idx >> 3) & 63;
    int j = idx & 7;
    int k = kk * 16 + 8 * (l >> 5) + j;
    int col = l & 31;
    int kx = col >> 1;
    int t = (kx * k) & 511;
    float sv, cv;
    sincosf(TWO_PI * (float)t / 512.0f, &sv, &cv);
    E[idx] = bf16_rn((col & 1) ? -sv : cv);
  } else if (idx < 49152) {
    int idx2 = idx - 16384;
    int mt = idx2 >> 14;
    int rem = idx2 & 16383;
    int kk = rem >> 9;
    int l = (rem >> 3) & 63;
    int j = rem & 7;
    int h = kk * 16 + 8 * (l >> 5) + j;
    int kyc = l & 31;
    int kyp = mt * 16 + (kyc >> 1);
    int ky = (kyp < 16) ? kyp : (kyp + 480);
    int t = (ky * h) & 511;
    float sv, cv;
    sincosf(TWO_PI * (float)t / 512.0f, &sv, &cv);
    E[idx] = bf16_rn((kyc & 1) ? -sv : cv);
  } else {
    int rem = idx - 49152;                 // 0..16383
    int ntile = rem >> 10;
    int s = (rem >> 9) & 1;
    int l = (rem >> 3) & 63;
    int j = rem & 7;
    int K = s * 16 + 8 * (l >> 5) + j;
    int k = K >> 1, c = K & 1;
    int w = ntile * 32 + (l & 31);
    int t = (k * w) & 511;
    float sv, cv;
    sincosf(TWO_PI * (float)t / 512.0f, &sv, &cv);
    float wk = (k == 0) ? 1.0f : 2.0f;
    float inv = 1.0f / 262144.0f;
    E[idx] = bf16_rn(inv * wk * (c ? -sv : cv));
  }
}

// ---------------- fwd: x image -> F (unchanged from round 5) -------------
__global__ __launch_bounds__(512) void fwd_kernel(const float* __restrict__ x,
                                                  const float* __restrict__ Ef,
                                                  const float* __restrict__ E2f,
                                                  float* __restrict__ F) {
  __shared__ char lds[135168];
  short* E2l = (short*)lds;                 // [mt 2][kk 32][64][8]  64 KB
  short* Xh  = (short*)(lds + 65536);       // [kc 32][64][8]        32 KB
  short* Xl  = (short*)(lds + 98304);       //                       32 KB
  float* red = (float*)(lds + 65536);       // alias Xh
  short* Ah  = (short*)(lds + 131072);      // [kc2 2][64][8]         2 KB
  short* Al  = (short*)(lds + 133120);      //                        2 KB
  float* Pbuf = (float*)(lds + 65536);      // final reduce (alias)

  const int tid = threadIdx.x;
  const int l = tid & 63;
  const int wid = tid >> 6;
  const int bi = blockIdx.x;
  const float* xb = x + (size_t)bi * (Hh * Ww);

  {
    const float4* Eg = (const float4*)E2f;
    float4* El4 = (float4*)E2l;
    #pragma unroll
    for (int j = 0; j < 8; ++j) El4[tid + j * 512] = Eg[tid + j * 512];
  }
  short8 e1[4];
  {
    const short* Eg = (const short*)Ef;
    #pragma unroll
    for (int c = 0; c < 4; ++c)
      e1[c] = *(const short8*)(Eg + ((size_t)(4 * wid + c) * 64 + l) * 8);
  }

  const int hb = (l >> 1) & 1;
  const int jfr = 4 * (l & 1);
  const int kc0 = l >> 2;

  float4 rv[8];
  #pragma unroll
  for (int j = 0; j < 4; ++j) {
    const float* rowp = xb + (size_t)(wid * 4 + j) * 512;
    rv[2 * j]     = *(const float4*)(rowp + 4 * l);
    rv[2 * j + 1] = *(const float4*)(rowp + 256 + 4 * l);
  }

  f32x16 acc1 = {0.f,0.f,0.f,0.f,0.f,0.f,0.f,0.f,0.f,0.f,0.f,0.f,0.f,0.f,0.f,0.f};
  f32x16 acc2 = {0.f,0.f,0.f,0.f,0.f,0.f,0.f,0.f,0.f,0.f,0.f,0.f,0.f,0.f,0.f,0.f};

  const int mt2 = wid & 1, kc2w = (wid >> 1) & 1, part2 = wid >> 2;

  for (int s = 0; s < 16; ++s) {
    if (s > 0) {
      short8 a2 = *(const short8*)&E2l[((mt2 * 32 + ((s - 1) * 2 + kc2w)) * 64 + l) * 8];
      short8 b2 = part2 ? *(const short8*)&Al[(kc2w * 64 + l) * 8]
                        : *(const short8*)&Ah[(kc2w * 64 + l) * 8];
      acc2 = __builtin_amdgcn_mfma_f32_32x32x16_bf16(a2, b2, acc2, 0, 0, 0);
    }
    #pragma unroll
    for (int j = 0; j < 4; ++j) {
      #pragma unroll
      for (int hf = 0; hf < 2; ++hf) {
        int kc = hf * 16 + kc0;
        int lanep = (wid * 4 + j) + 32 * hb;
        int off = ((kc * 64) + (lanep ^ (kc & 7))) * 8 + jfr;
        uint2 h2, l2;
        split4(rv[2 * j + hf], h2, l2);
        *(uint2*)&Xh[off] = h2;
        *(uint2*)&Xl[off] = l2;
      }
    }
    if (s < 15) {
      #pragma unroll
      for (int j = 0; j < 4; ++j) {
        const float* rowp = xb + (size_t)((s + 1) * 32 + wid * 4 + j) * 512;
        rv[2 * j]     = *(const float4*)(rowp + 4 * l);
        rv[2 * j + 1] = *(const float4*)(rowp + 256 + 4 * l);
      }
    }
    __syncthreads();
    #pragma unroll
    for (int c = 0; c < 4; ++c) {
      int kc = 4 * wid + c;
      int slot = ((kc * 64) + (l ^ (kc & 7))) * 8;
      short8 hi = *(const short8*)&Xh[slot];
      short8 lo = *(const short8*)&Xl[slot];
      acc1 = __builtin_amdgcn_mfma_f32_32x32x16_bf16(hi, e1[c], acc1, 0, 0, 0);
      acc1 = __builtin_amdgcn_mfma_f32_32x32x16_bf16(lo, e1[c], acc1, 0, 0, 0);
    }
    __syncthreads();
    #pragma unroll
    for (int q = 0; q < 4; ++q)
      *(float4*)&red[((wid * 4 + q) * 64 + l) * 4] =
          make_float4(acc1[4*q], acc1[4*q+1], acc1[4*q+2], acc1[4*q+3]);
    #pragma unroll
    for (int r = 0; r < 16; ++r) acc1[r] = 0.f;
    __syncthreads();
    if (wid < 4) {
      const int q = wid;
      float4 sum = make_float4(0.f, 0.f, 0.f, 0.f);
      #pragma unroll
      for (int w = 0; w < 8; ++w) {
        float4 v = *(const float4*)&red[((w * 4 + q) * 64 + l) * 4];
        sum.x += v.x; sum.y += v.y; sum.z += v.z; sum.w += v.w;
      }
      uint2 h2, l2;
      split4(sum, h2, l2);
      int off = ((q >> 1) * 64 + ((l & 31) + 32 * (q & 1))) * 8 + 4 * (l >> 5);
      *(uint2*)&Ah[off] = h2;
      *(uint2*)&Al[off] = l2;
    }
    __syncthreads();
  }
  {
    short8 a2 = *(const short8*)&E2l[((mt2 * 32 + (15 * 2 + kc2w)) * 64 + l) * 8];
    short8 b2 = part2 ? *(const short8*)&Al[(kc2w * 64 + l) * 8]
                      : *(const short8*)&Ah[(kc2w * 64 + l) * 8];
    acc2 = __builtin_amdgcn_mfma_f32_32x32x16_bf16(a2, b2, acc2, 0, 0, 0);
  }
  #pragma unroll
  for (int r4 = 0; r4 < 4; ++r4)
    *(float4*)&Pbuf[((wid * 4 + r4) * 64 + l) * 4] =
        make_float4(acc2[4*r4], acc2[4*r4+1], acc2[4*r4+2], acc2[4*r4+3]);
  __syncthreads();

  if (wid < 2) {
    const int mt = wid;
    float S[16];
    #pragma unroll
    for (int r = 0; r < 16; ++r) S[r] = 0.f;
    #pragma unroll
    for (int p = 0; p < 4; ++p) {
      #pragma unroll
      for (int r4 = 0; r4 < 4; ++r4) {
        float4 v = *(const float4*)&Pbuf[(((mt + 2 * p) * 4 + r4) * 64 + l) * 4];
        S[4*r4]   += v.x; S[4*r4+1] += v.y; S[4*r4+2] += v.z; S[4*r4+3] += v.w;
      }
    }
    const int c = l & 1;
    #pragma unroll
    for (int q = 0; q < 8; ++q) {
      int r0 = 2 * q;
      float T = __shfl_xor(S[r0 + 1], 1, 64);
      float val = c ? (S[r0] + T) : (S[r0] - T);
      int kyp_loc = ((r0 & 3) >> 1) + 4 * (r0 >> 2) + 2 * (l >> 5);
      F[((size_t)bi * 32 + mt * 16 + kyp_loc) * 32 + (l & 31)] = val;
    }
  }
}

// ---------------- mix: F -> G (hoisted; identical fmaf chain) ------------
__global__ __launch_bounds__(512) void mix_kernel(const float* __restrict__ F,
    const float* __restrict__ w1r, const float* __restrict__ w1i,
    const float* __restrict__ w2r, const float* __restrict__ w2i,
    float* __restrict__ G) {
  const int tid = threadIdx.x;
  const int b = blockIdx.x >> 5;
  const int o = blockIdx.x & 31;
  const int kyp = tid >> 4;
  const int kx = tid & 15;
  const bool top = kyp < 16;
  const int m = top ? kyp : (kyp - 16);
  const float* wr = top ? w1r : w2r;
  const float* wi = top ? w1i : w2i;
  float gr = 0.f, gi = 0.f;
  for (int i = 0; i < CI; ++i) {
    float2 f = *(const float2*)&F[(((size_t)b * CI + i) * KYp + kyp) * (HM * 2) + kx * 2];
    size_t wo = (((size_t)i * CO + o) * HM + m) * HM + kx;
    float wrv = wr[wo], wiv = wi[wo];
    gr = fmaf(f.x, wrv, gr); gr = fmaf(-f.y, wiv, gr);
    gi = fmaf(f.x, wiv, gi); gi = fmaf(f.y, wrv, gi);
  }
  size_t go = ((size_t)blockIdx.x * KYp + kyp) * (HM * 2) + kx * 2;
  *(float2*)(G + go) = make_float2(gr, gi);
}

// ---------------- bwd: G -> y. 2048 blocks of 64 rows (b,o,chunk).
//  LDS 16 KB. t2 = MFMA -> DIRECT nontemporal stores from accumulators
//  (no ybuf, no t2 barriers): stores issue immediately and drain under
//  the next mtile's / next block's compute.  [R16 best: 109.9 us]
__global__ __launch_bounds__(512, 4) void bwd_kernel(const float* __restrict__ G,
    const float* __restrict__ bias, const float* __restrict__ T2f,
    float* __restrict__ y) {
  __shared__ char lds[16384];
  short* Ah   = (short*)lds;                // [mt_loc 2][s 2][64][8]  4 KB
  short* Al   = (short*)(lds + 4096);       //                         4 KB
  float* Gs   = (float*)(lds + 8192);       // [kyp 32][kx 16][2]      4 KB
  float* ct   = (float*)(lds + 12288);      // 2 KB
  float* st   = (float*)(lds + 14336);      // 2 KB

  const int tid = threadIdx.x;
  const int l = tid & 63;
  const int wid = tid >> 6;
  const int bo = blockIdx.x >> 3;      // b*CO + o
  const int chunk = blockIdx.x & 7;    // 64-row chunk
  const int o = bo & 31;
  const float bv = bias[o];

  // B-fragments for this wave's 2 ntiles -> 16 VGPRs
  short8 bfr[4];
  {
    const short* Tg = (const short*)T2f;
    #pragma unroll
    for (int q = 0; q < 4; ++q) {
      int nt = wid * 2 + (q >> 1);
      int s = q & 1;
      bfr[q] = *(const short8*)(Tg + ((size_t)(nt * 2 + s) * 64 + l) * 8);
    }
  }
  // twiddle table + G stage (4 KB)
  {
    float sv, cv;
    sincosf(TWO_PI * (float)tid / 512.0f, &sv, &cv);
    ct[tid] = cv;
    st[tid] = sv;
    if (tid < 256)
      ((float4*)Gs)[tid] = ((const float4*)(G + (size_t)bo * (KYp * HM * 2)))[tid];
  }
  __syncthreads();

  // ---- t1: wave wid = kx pair (2*wid, 2*wid+1); lane = row in chunk ----
  {
    const int r = l;                   // row within chunk
    const int h = chunk * 64 + r;
    const int kxh = wid;               // kx 2*kxh, 2*kxh+1
    float gr[2], gi[2];
    gr[0] = gr[1] = gi[0] = gi[1] = 0.f;
    #pragma unroll 4
    for (int kyp = 0; kyp < 32; ++kyp) {
      const int ky = (kyp < 16) ? kyp : (kyp + 480);
      const int t = (ky * h) & 511;
      const float cc = ct[t], ss = st[t];
      float4 gv = *(const float4*)&Gs[kyp * 32 + kxh * 4];
      #pragma unroll
      for (int k = 0; k < 2; ++k) {
        float Gr = ((const float*)&gv)[2 * k];
        float Gi = ((const float*)&gv)[2 * k + 1];
        gr[k] = fmaf(Gr, cc, gr[k]); gr[k] = fmaf(-Gi, ss, gr[k]);
        gi[k] = fmaf(Gr, ss, gi[k]); gi[k] = fmaf(Gi, cc, gi[k]);
      }
    }
    // frag write: K = 4*kxh + {0..3}; s=(kxh>>2), half=(kxh>>1)&1, j0=4*(kxh&1)
    const int mt_loc = r >> 5;
    const int rr = r & 31;
    const int s = kxh >> 2;
    const int halfk = (kxh >> 1) & 1;
    const int j0 = 4 * (kxh & 1);
    float4 va = make_float4(gr[0], gi[0], gr[1], gi[1]);
    uint2 ha, la;
    split4(va, ha, la);
    int off = ((mt_loc * 2 + s) * 64 + rr + 32 * halfk) * 8 + j0;
    *(uint2*)&Ah[off] = ha;
    *(uint2*)&Al[off] = la;
  }
  __syncthreads();

  // ---- t2: per mtile: 2 MFMA accs -> direct NT stores (no staging) ----
  {
    float* yb = y + (size_t)bo * (Hh * Ww) + (size_t)chunk * 64 * Ww;
    const int colA = (wid * 2) * 32 + (l & 31);
    const int colB = (wid * 2 + 1) * 32 + (l & 31);
    const int rq = 4 * (l >> 5);
    #pragma unroll
    for (int mt = 0; mt < 2; ++mt) {
      short8 a_h0 = *(const short8*)&Ah[((mt * 2 + 0) * 64 + l) * 8];
      short8 a_l0 = *(const short8*)&Al[((mt * 2 + 0) * 64 + l) * 8];
      short8 a_h1 = *(const short8*)&Ah[((mt * 2 + 1) * 64 + l) * 8];
      short8 a_l1 = *(const short8*)&Al[((mt * 2 + 1) * 64 + l) * 8];
      f32x16 accA, accB;
      #pragma unroll
      for (int r = 0; r < 16; ++r) { accA[r] = bv; accB[r] = bv; }
      accA = __builtin_amdgcn_mfma_f32_32x32x16_bf16(a_h0, bfr[0], accA, 0, 0, 0);
      accA = __builtin_amdgcn_mfma_f32_32x32x16_bf16(a_l0, bfr[0], accA, 0, 0, 0);
      accA = __builtin_amdgcn_mfma_f32_32x32x16_bf16(a_h1, bfr[1], accA, 0, 0, 0);
      accA = __builtin_amdgcn_mfma_f32_32x32x16_bf16(a_l1, bfr[1], accA, 0, 0, 0);
      accB = __builtin_amdgcn_mfma_f32_32x32x16_bf16(a_h0, bfr[2], accB, 0, 0, 0);
      accB = __builtin_amdgcn_mfma_f32_32x32x16_bf16(a_l0, bfr[2], accB, 0, 0, 0);
      accB = __builtin_amdgcn_mfma_f32_32x32x16_bf16(a_h1, bfr[3], accB, 0, 0, 0);
      accB = __builtin_amdgcn_mfma_f32_32x32x16_bf16(a_l1, bfr[3], accB, 0, 0, 0);
      #pragma unroll
      for (int r = 0; r < 16; ++r) {
        int row = mt * 32 + (r & 3) + 8 * (r >> 2) + rq;
        __builtin_nontemporal_store(accA[r], &yb[(size_t)row * Ww + colA]);
        __builtin_nontemporal_store(accB[r], &yb[(size_t)row * Ww + colB]);
      }
    }
  }
}

extern "C" void kernel_launch(void* const* d_in, const int* in_sizes, int n_in,
                              void* d_out, int out_size, void* d_ws, size_t ws_size,
                              hipStream_t stream) {
  const float* x    = (const float*)d_in[0];
  const float* w1r  = (const float*)d_in[1];
  const float* w1i  = (const float*)d_in[2];
  const float* w2r  = (const float*)d_in[3];
  const float* w2i  = (const float*)d_in[4];
  const float* bias = (const float*)d_in[5];
  float* y  = (float*)d_out;
  float* ws = (float*)d_ws;
  float* F   = ws + F_OFF;
  float* G   = ws + G_OFF;
  float* E   = ws + g_OFF;           // 32 KB
  float* E2c = ws + g_OFF + 8192;    // 64 KB
  float* T2f = ws + g_OFF + 24576;   // 32 KB

  hipLaunchKernelGGL(e_init_kernel, dim3(256), dim3(256), 0, stream, E);
  hipLaunchKernelGGL(fwd_kernel, dim3(Bb * CI), dim3(512), 0, stream, x, E, E2c, F);
  hipLaunchKernelGGL(mix_kernel, dim3(Bb * CO), dim3(512), 0, stream, F,
                     w1r, w1i, w2r, w2i, G);
  hipLaunchKernelGGL(bwd_kernel, dim3(Bb * CO * 8), dim3(512), 0, stream, G,
                     bias, T2f, y);
}